// Round 13
// baseline (289.496 us; speedup 1.0000x reference)
//
#include <hip/hip_runtime.h>

#define NPIX   1024   // 32*32
#define NEH    992    // horizontal edges 32*31
#define NEDGE  1984   // + vertical 31*32
#define SORTN  2048
#define CHUNK  8      // labels per phase-2 pass
#define NMERGE 1023
#define NIL    0xFFFFu

__device__ __forceinline__ void edge_ab(int e, int& a, int& b) {
    if (e < NEH) { int y = e / 31; int x = e - y * 31; a = y * 32 + x; b = a + 1; }
    else         { int ev = e - NEH; a = ev; b = ev + 32; }
}

__device__ __forceinline__ uint4 add4(uint4 x, uint4 y) {
    return make_uint4(x.x + y.x, x.y + y.y, x.z + y.z, x.w + y.w);
}
__device__ __forceinline__ uint4 sub4(uint4 x, uint4 y) {
    return make_uint4(x.x - y.x, x.y - y.y, x.z - y.z, x.w - y.w);
}

// wave-uniform broadcast via v_readlane (VALU/SALU class; no LDS round-trip)
__device__ __forceinline__ unsigned rdl32(unsigned v, int lane) {
    return (unsigned)__builtin_amdgcn_readlane((int)v, lane);
}
__device__ __forceinline__ unsigned long long rdl64(unsigned long long v, int lane) {
    unsigned lo = (unsigned)__builtin_amdgcn_readlane((int)(unsigned)v, lane);
    unsigned hi = (unsigned)__builtin_amdgcn_readlane((int)(unsigned)(v >> 32), lane);
    return ((unsigned long long)hi << 32) | lo;
}

// ============================ fully fused kernel ============================
// Per-(tile,sgn) block, 256 threads, 2 blocks/CU (LDS just under 64 KiB):
//   1. load tile -> pT/bgS; init DSU state
//   2. CCL of background (wave-0 register sweeps; labS/cntS alias 'big') -> pixLab, K
//   3. bitonic sort of edge keys IN 'big' (all 256 threads); Kruskal reads edge ids
//      straight from the sorted keys (no orderS array -> stays under the LDS cliff)
//   4. hybrid Kruskal on wave 0: gen-tagged priority-claim bulk rounds + chain-scan
//      tail (common-root endgame committed via wave prefix-scan) + serial
//      register-log fallback. Exact serial-Kruskal record equivalence.
//   5. Wyllie list-ranking + chunked label prefix dots + loss ('big' recycled
//      only after the post-Kruskal barrier).
__global__ __launch_bounds__(256, 2)
void malis_all(const float* __restrict__ t_glob,
               const float* __restrict__ p_glob,
               float* __restrict__ out) {
    const int tid = threadIdx.x;
    const int wg  = blockIdx.x;
    const int sgn = wg & 1;
    const int tileId = wg >> 1;
    const int bat = tileId >> 6;
    const int tile = tileId & 63;
    const int tr = tile >> 3, tc = tile & 7;

    __shared__ unsigned short parentS[NPIX];            // 2048
    __shared__ unsigned long long nodeS[NPIX];          // 8192
    __shared__ unsigned short nextS[NPIX];              // 2048
    __shared__ unsigned int   mRecA[NMERGE];            // 4092
    __shared__ unsigned int   mRecB[NMERGE];            // 4092
    __shared__ unsigned int   mSaSb[NMERGE];            // 4092
    __shared__ unsigned int   commonW[NMERGE];          // 4092
    __shared__ unsigned short mEd[NMERGE];              // 2046
    __shared__ float          pT[NPIX];                 // 4096
    __shared__ unsigned char  bgS[NPIX];                // 1024
    __shared__ unsigned short pixLab[NPIX];             // 2048
    __shared__ unsigned short posS[NPIX];               // 2048
    __shared__ unsigned int   claimS[NPIX];             // 4096 (gen-tagged, never cleared)
    __shared__ __align__(16) unsigned long long big[2564];  // 20512 arena: CCL | keys | rank | prefix
    __shared__ int   mCountSh, kprimeSh;
    __shared__ unsigned wsumSh;
    __shared__ float lossSh;

    // ---- 1. load tile + init DSU ----
    for (int i = tid; i < NPIX; i += 256) {
        int y = i >> 5, x = i & 31;
        int gidx = bat * 65536 + (tr * 32 + y) * 256 + (tc * 32 + x);
        float tv = t_glob[gidx];
        unsigned bg = (tv == 0.0f) ? 1u : 0u;
        pT[i] = p_glob[gidx];
        bgS[i] = (unsigned char)bg;
        parentS[i] = (unsigned short)i;
        nodeS[i] = ((unsigned long long)i << 48) | ((unsigned long long)i << 32)
                 | (1ULL << 16) | (unsigned long long)bg;
        nextS[i] = (unsigned short)NIL;
        claimS[i] = 0xFFFFFFFFu;
    }
    __syncthreads();

    // ---- 2. CCL of background (labS/cntS alias big) ----
    unsigned short* labS = (unsigned short*)big;
    unsigned int*   cntS = (unsigned int*)(((char*)big) + 2048);
    if (tid < 64) {
        const int lane = tid;
        if (lane < 32) {
            #pragma unroll
            for (int x = 0; x < 32; x++) {
                int i = lane * 32 + x;
                labS[i] = bgS[i] ? (unsigned short)i : (unsigned short)NIL;
            }
        }
        while (true) {
            bool changed = false;
            if (lane < 32) {
                const int base = lane * 32;
                unsigned short v[32];
                #pragma unroll
                for (int x = 0; x < 32; x++) v[x] = labS[base + x];
                unsigned run = NIL;
                #pragma unroll
                for (int x = 0; x < 32; x++) {
                    unsigned val = v[x];
                    if (val == NIL) { run = NIL; }
                    else { unsigned nv = min(run, val); changed |= (nv != val); v[x] = (unsigned short)nv; run = nv; }
                }
                run = NIL;
                #pragma unroll
                for (int x = 31; x >= 0; x--) {
                    unsigned val = v[x];
                    if (val == NIL) { run = NIL; }
                    else { unsigned nv = min(run, val); changed |= (nv != val); v[x] = (unsigned short)nv; run = nv; }
                }
                #pragma unroll
                for (int x = 0; x < 32; x++) labS[base + x] = v[x];
            }
            if (lane < 32) {
                unsigned short c[32];
                #pragma unroll
                for (int k = 0; k < 32; k++) c[k] = labS[k * 32 + lane];
                unsigned run = NIL;
                #pragma unroll
                for (int k = 0; k < 32; k++) {
                    unsigned val = c[k];
                    if (val == NIL) { run = NIL; }
                    else { unsigned nv = min(run, val); changed |= (nv != val); c[k] = (unsigned short)nv; run = nv; }
                }
                run = NIL;
                #pragma unroll
                for (int k = 31; k >= 0; k--) {
                    unsigned val = c[k];
                    if (val == NIL) { run = NIL; }
                    else { unsigned nv = min(run, val); changed |= (nv != val); c[k] = (unsigned short)nv; run = nv; }
                }
                #pragma unroll
                for (int k = 0; k < 32; k++) labS[k * 32 + lane] = c[k];
            }
            if (!__any(changed)) break;
        }
    }
    __syncthreads();

    // label compaction: components with >=2 px get compact ids
    for (int i = tid; i < NPIX; i += 256) cntS[i] = 0;
    if (tid == 0) kprimeSh = 0;
    __syncthreads();
    for (int i = tid; i < NPIX; i += 256)
        if (bgS[i]) atomicAdd(&cntS[labS[i]], 1u);
    __syncthreads();
    for (int i = tid; i < NPIX; i += 256) {
        if (bgS[i] && (int)labS[i] == i) {
            unsigned id = (cntS[i] >= 2) ? (unsigned)atomicAdd(&kprimeSh, 1) : NIL;
            cntS[i] = id;
        }
    }
    __syncthreads();
    for (int i = tid; i < NPIX; i += 256)
        pixLab[i] = bgS[i] ? (unsigned short)cntS[labS[i]] : (unsigned short)NIL;
    __syncthreads();

    // ---- 3. bitonic sort of edge keys in big ----
    unsigned long long* keys = big;
    for (int k = tid; k < SORTN; k += 256) {
        unsigned long long key = 0ULL;
        if (k < NEDGE) {
            int a, b; edge_ab(k, a, b);
            float cost = pT[a] + pT[b];
            int nfg = (int)(!bgS[a]) + (int)(!bgS[b]);
            if (sgn == 0) { if (nfg == 2) cost = 20.0f; }
            else          { if (nfg == 0) cost = 0.0f;  }
            key = ((unsigned long long)__float_as_uint(cost) << 16)
                | (unsigned long long)(0xFFFFu - (unsigned)k);
        }
        keys[k] = key;   // pads sort last
    }
    __syncthreads();
    for (int kk = 2; kk <= SORTN; kk <<= 1) {
        for (int jj = kk >> 1; jj > 0; jj >>= 1) {
            for (int i = tid; i < SORTN; i += 256) {
                int ixj = i ^ jj;
                if (ixj > i) {
                    unsigned long long A = keys[i], Bv = keys[ixj];
                    bool descBlk = ((i & kk) == 0);
                    if ((A < Bv) == descBlk) { keys[i] = Bv; keys[ixj] = A; }
                }
            }
            __syncthreads();
        }
    }

    // ---- 4. hybrid Kruskal on wave 0 (edge ids read from sorted keys) ----
    if (tid < 64) {
        const int lane = tid;
        int m = 0;
        unsigned gen = 1u << 24;                         // strictly decreasing claim gen
        for (int kb = 0; kb < NEDGE; kb += 64) {         // 31 exact batches
            int e = 0xFFFF - (int)(keys[kb + lane] & 0xFFFFULL);
            int a, b; edge_ab(e, a, b);
            unsigned ra = (unsigned)a, rb = (unsigned)b;
            while (true) {                               // concurrent path-halving find
                unsigned pa = parentS[ra];
                unsigned pb = parentS[rb];
                if (pa == ra && pb == rb) break;
                if (pa != ra) { unsigned ga = parentS[pa]; parentS[ra] = (unsigned short)ga; ra = ga; }
                if (pb != rb) { unsigned gb = parentS[pb]; parentS[rb] = (unsigned short)gb; rb = gb; }
            }
            bool pending = (ra != rb);
            bool committed = false;
            unsigned recA = 0, recB = 0, recSS = 0;

            // ---- bulk gen-tagged claim rounds ----
            int winners = 64;
            while (__any(pending) && winners >= 6) {
                gen--;
                unsigned myval = (gen << 6) | (unsigned)lane;
                if (pending) {
                    atomicMin(&claimS[ra], myval);
                    atomicMin(&claimS[rb], myval);
                }
                bool win = pending && (claimS[ra] == myval) && (claimS[rb] == myval);
                if (win) {
                    unsigned long long nA = nodeS[ra], nB = nodeS[rb];
                    unsigned cons = ra, surv = rb;
                    unsigned szAu = (unsigned)(nA >> 16) & 0xFFFFu;
                    unsigned szBu = (unsigned)(nB >> 16) & 0xFFFFu;
                    if (szAu > szBu) {
                        unsigned t = cons; cons = surv; surv = t;
                        unsigned long long tn = nA; nA = nB; nB = tn;
                    }
                    unsigned headA = (unsigned)(nA >> 48);
                    unsigned tailA = (unsigned)(nA >> 32) & 0xFFFFu;
                    unsigned szA   = (unsigned)(nA >> 16) & 0xFFFFu;
                    unsigned slA   = (unsigned)nA & 0xFFFFu;
                    unsigned headB = (unsigned)(nB >> 48);
                    unsigned tailB = (unsigned)(nB >> 32) & 0xFFFFu;
                    unsigned szB   = (unsigned)(nB >> 16) & 0xFFFFu;
                    unsigned slB   = (unsigned)nB & 0xFFFFu;
                    unsigned long long merged =
                          ((unsigned long long)headA << 48)
                        | ((unsigned long long)tailB << 32)
                        | ((unsigned long long)(szA + szB) << 16)
                        | (unsigned long long)(slA + slB);
                    parentS[cons] = (unsigned short)surv;
                    nodeS[surv]   = merged;
                    nextS[tailA]  = (unsigned short)headB;
                    recA = (headA << 16) | headB;
                    recB = (szA << 16) | szB;
                    recSS = slA * slB;
                    committed = true;
                    pending = false;
                }
                winners = (int)__popcll(__ballot(win));
                if (pending) {
                    while (true) {
                        unsigned pa = parentS[ra];
                        unsigned pb = parentS[rb];
                        if (pa == ra && pb == rb) break;
                        if (pa != ra) { unsigned ga = parentS[pa]; parentS[ra] = (unsigned short)ga; ra = ga; }
                        if (pb != rb) { unsigned gb = parentS[pb]; parentS[rb] = (unsigned short)gb; rb = gb; }
                    }
                    if (ra == rb) pending = false;
                }
            }

            unsigned long long cmB = __ballot(committed);
            if (committed) {
                int idx = m + (int)__popcll(cmB & ((1ULL << lane) - 1ULL));
                mRecA[idx] = recA;
                mRecB[idx] = recB;
                mSaSb[idx] = recSS;
                mEd[idx]   = (unsigned short)e;
            }
            m += (int)__popcll(cmB);

            // ---- tail ----
            int logCount = 0;
            unsigned long long candm0 = __ballot(pending);
            if (candm0 != 0ULL) {
                unsigned long long na = 0, nb = 0;
                if (pending) { na = nodeS[ra]; nb = nodeS[rb]; }   // fresh post-bulk
                int j0 = __ffsll((long long)candm0) - 1;
                unsigned Ra = rdl32(ra, j0), Rb = rdl32(rb, j0);
                unsigned long long mAc = __ballot(pending && (ra == Ra || rb == Ra));
                unsigned long long mBc = __ballot(pending && (ra == Rb || rb == Rb));
                unsigned R = (__popcll(mAc) >= __popcll(mBc)) ? Ra : Rb;
                bool onR  = pending && ((ra == R) != (rb == R));
                bool offR = pending && (ra != R) && (rb != R);

                if (!__any(offR)) {
                    // ======== chain-scan ========
                    unsigned cons = 0;
                    unsigned long long cnode = 0;
                    if (onR) { cons = (ra == R) ? rb : ra; cnode = (ra == R) ? nb : na; }
                    gen--;
                    unsigned myval = (gen << 6) | (unsigned)lane;
                    if (onR) atomicMin(&claimS[cons], myval);
                    bool valid = onR && (claimS[cons] == myval);   // dedup: losers are cycle-skips
                    unsigned long long vm = __ballot(valid);
                    if (vm != 0ULL) {
                        unsigned long long rnode = (R == Ra) ? rdl64(na, j0) : rdl64(nb, j0);
                        unsigned headR0 = (unsigned)(rnode >> 48);
                        unsigned tailR0 = (unsigned)(rnode >> 32) & 0xFFFFu;
                        unsigned szR0   = (unsigned)(rnode >> 16) & 0xFFFFu;
                        unsigned slR0   = (unsigned)rnode & 0xFFFFu;
                        unsigned headA = valid ? (unsigned)(cnode >> 48) : 0u;
                        unsigned tailA = valid ? (unsigned)(cnode >> 32) & 0xFFFFu : 0u;
                        unsigned szA   = valid ? (unsigned)(cnode >> 16) & 0xFFFFu : 0u;
                        unsigned slA   = valid ? (unsigned)cnode & 0xFFFFu : 0u;
                        unsigned s1 = szA, s2 = slA;           // inclusive scans
                        #pragma unroll
                        for (int d = 1; d < 64; d <<= 1) {
                            unsigned o1 = __shfl_up(s1, d, 64);
                            unsigned o2 = __shfl_up(s2, d, 64);
                            if (lane >= d) { s1 += o1; s2 += o2; }
                        }
                        unsigned szPre = s1 - szA, slPre = s2 - slA;    // exclusive
                        unsigned long long below = vm & ((1ULL << lane) - 1ULL);
                        int pv = 63 - (int)__clzll((long long)(below | 1ULL));
                        unsigned hprev = __shfl(headA, below ? pv : 0, 64);
                        unsigned headB = below ? hprev : headR0;
                        unsigned szB = szR0 + szPre;
                        unsigned slB = slR0 + slPre;
                        if (valid) {
                            parentS[cons] = (unsigned short)R;
                            nextS[tailA]  = (unsigned short)headB;
                            int idx = m + (int)__popcll(below);
                            mRecA[idx] = (headA << 16) | headB;
                            mRecB[idx] = (szA << 16) | szB;
                            mSaSb[idx] = slA * slB;
                            mEd[idx]   = (unsigned short)e;
                        }
                        int last = 63 - (int)__clzll((long long)vm);
                        if (valid && lane == last) {
                            nodeS[R] = ((unsigned long long)headA << 48)
                                     | ((unsigned long long)tailR0 << 32)
                                     | ((unsigned long long)(szR0 + s1) << 16)
                                     | (unsigned long long)(slR0 + s2);
                        }
                        logCount = (int)__popcll(vm);
                    }
                } else {
                    // ======== serial register-log fallback ========
                    unsigned specAB = (ra << 16) | rb;
                    unsigned long long candm = candm0;
                    unsigned logRa  = 0xFFFFFFFFu;
                    unsigned logRbO = 0xFFFFFFFFu;
                    unsigned curRoot = 0xFFFFFFFFu;
                    unsigned long long logNode = 0;
                    while (candm != 0ULL) {
                        int j = __ffsll((long long)candm) - 1;
                        candm &= candm - 1ULL;
                        unsigned sAB = rdl32(specAB, j);
                        unsigned cra = sAB >> 16;
                        unsigned crb = sAB & 0xFFFFu;
                        unsigned long long hitA = __ballot(logRa == cra);
                        unsigned long long hitB = __ballot(logRa == crb);
                        if (hitA) cra = rdl32(curRoot, __ffsll((long long)hitA) - 1);
                        if (hitB) crb = rdl32(curRoot, __ffsll((long long)hitB) - 1);
                        if (cra == crb) continue;
                        unsigned ce = rdl32((unsigned)e, j);
                        unsigned long long hbA = __ballot(logRbO == cra);
                        unsigned long long hbB = __ballot(logRbO == crb);
                        unsigned long long cna = hbA ? rdl64(logNode, 63 - __clzll((long long)hbA)) : rdl64(na, j);
                        unsigned long long cnb = hbB ? rdl64(logNode, 63 - __clzll((long long)hbB)) : rdl64(nb, j);
                        unsigned cons = cra, surv = crb;
                        unsigned szAq = (unsigned)(cna >> 16) & 0xFFFFu;
                        unsigned szBq = (unsigned)(cnb >> 16) & 0xFFFFu;
                        if (szAq > szBq) {
                            unsigned t = cons; cons = surv; surv = t;
                            unsigned long long tn = cna; cna = cnb; cnb = tn;
                        }
                        unsigned headA = (unsigned)(cna >> 48);
                        unsigned tailA = (unsigned)(cna >> 32) & 0xFFFFu;
                        unsigned szA   = (unsigned)(cna >> 16) & 0xFFFFu;
                        unsigned slA   = (unsigned)cna & 0xFFFFu;
                        unsigned headB = (unsigned)(cnb >> 48);
                        unsigned tailB = (unsigned)(cnb >> 32) & 0xFFFFu;
                        unsigned szB   = (unsigned)(cnb >> 16) & 0xFFFFu;
                        unsigned slB   = (unsigned)cnb & 0xFFFFu;
                        unsigned long long merged =
                              ((unsigned long long)headA << 48)
                            | ((unsigned long long)tailB << 32)
                            | ((unsigned long long)(szA + szB) << 16)
                            | (unsigned long long)(slA + slB);
                        if (curRoot == cons) curRoot = surv;
                        if (lane == logCount) {
                            logRa = cons; logRbO = surv; curRoot = surv; logNode = merged;
                            parentS[cons] = (unsigned short)surv;
                            nodeS[surv]   = merged;
                            nextS[tailA]  = (unsigned short)headB;
                            int idx = m + logCount;
                            mRecA[idx] = (headA << 16) | headB;
                            mRecB[idx] = (szA << 16) | szB;
                            mSaSb[idx] = slA * slB;
                            mEd[idx]   = (unsigned short)ce;
                        }
                        logCount++;
                    }
                }
            }
            m += logCount;
        }
        if (lane == 0) mCountSh = m;
    }
    __syncthreads();
    const int M = mCountSh;
    const int K = kprimeSh;
    for (int j = tid; j < M; j += 256) commonW[j] = 0;

    // ---- 5a. Wyllie list ranking -> posS (big recycled) ----
    unsigned short* n0 = (unsigned short*)big;
    unsigned short* n1 = n0 + 1024;
    unsigned short* d0 = n0 + 2048;
    unsigned short* d1 = n0 + 3072;
    for (int i = tid; i < NPIX; i += 256) { n0[i] = nextS[i]; d0[i] = 1; }
    __syncthreads();
    for (int s = 0; s < 10; s++) {
        unsigned short* sn = (s & 1) ? n1 : n0;
        unsigned short* sd = (s & 1) ? d1 : d0;
        unsigned short* dn = (s & 1) ? n0 : n1;
        unsigned short* dd = (s & 1) ? d0 : d1;
        for (int i = tid; i < NPIX; i += 256) {
            unsigned nx = sn[i];
            unsigned dv = sd[i];
            if (nx != NIL) { dv += sd[nx]; nx = sn[nx]; }
            dn[i] = (unsigned short)nx;
            dd[i] = (unsigned short)dv;
        }
        __syncthreads();
    }
    for (int i = tid; i < NPIX; i += 256)
        posS[i] = (unsigned short)(NPIX - (int)d0[i]);
    __syncthreads();

    // ---- 5b. chunked label prefix sums + per-merge dots ----
    unsigned*       P32 = (unsigned*)big;
    uint4*          P4  = (uint4*)big;
    unsigned*       scr = P32 + 4100;
    uint4*          S4  = (uint4*)scr;
    unsigned short* P16 = (unsigned short*)big;
    for (int base = 0; base < K; base += CHUNK) {
        for (int idx = tid; idx < 4100; idx += 256) P32[idx] = 0;
        __syncthreads();
        for (int i = tid; i < NPIX; i += 256) {
            unsigned l = pixLab[i];
            if (l != NIL && l >= (unsigned)base && l < (unsigned)(base + CHUNK))
                P16[(posS[i] + 1) * 8 + (l - base)] = 1;
        }
        __syncthreads();
        {
            int r0 = tid * 4 + 1;
            uint4 acc = P4[r0];
            for (int rr = r0 + 1; rr <= r0 + 3; rr++) { acc = add4(acc, P4[rr]); P4[rr] = acc; }
            S4[tid] = acc;
            __syncthreads();
            if (tid < 64) {
                uint4 s0 = S4[tid * 4], s1 = S4[tid * 4 + 1], s2 = S4[tid * 4 + 2], s3 = S4[tid * 4 + 3];
                uint4 t1 = add4(s0, s1), t2 = add4(t1, s2), t3 = add4(t2, s3);
                uint4 run = t3;
                #pragma unroll
                for (int d = 1; d < 64; d <<= 1) {
                    uint4 o;
                    o.x = __shfl_up(run.x, d, 64);
                    o.y = __shfl_up(run.y, d, 64);
                    o.z = __shfl_up(run.z, d, 64);
                    o.w = __shfl_up(run.w, d, 64);
                    if (tid >= d) run = add4(run, o);
                }
                uint4 off = sub4(run, t3);
                S4[tid * 4]     = add4(s0, off);
                S4[tid * 4 + 1] = add4(t1, off);
                S4[tid * 4 + 2] = add4(t2, off);
                S4[tid * 4 + 3] = add4(t3, off);
            }
            __syncthreads();
            if (tid > 0) {
                uint4 off = S4[tid - 1];
                for (int rr = r0; rr <= r0 + 3; rr++) P4[rr] = add4(P4[rr], off);
            }
        }
        __syncthreads();
        for (int j = tid; j < M; j += 256) {
            unsigned recA = mRecA[j], recB = mRecB[j];
            unsigned aS = posS[recA >> 16];
            unsigned bS = posS[recA & 0xFFFFu];
            uint4 da = sub4(P4[aS + (recB >> 16)], P4[aS]);
            uint4 db = sub4(P4[bS + (recB & 0xFFFFu)], P4[bS]);
            unsigned acc;
            acc  = (da.x & 0xFFFFu) * (db.x & 0xFFFFu) + (da.x >> 16) * (db.x >> 16);
            acc += (da.y & 0xFFFFu) * (db.y & 0xFFFFu) + (da.y >> 16) * (db.y >> 16);
            acc += (da.z & 0xFFFFu) * (db.z & 0xFFFFu) + (da.z >> 16) * (db.z >> 16);
            acc += (da.w & 0xFFFFu) * (db.w & 0xFFFFu) + (da.w >> 16) * (db.w >> 16);
            commonW[j] += acc;
        }
        __syncthreads();
    }

    // ---- 5c. normalize + mask + loss ----
    if (tid == 0) { wsumSh = 0; lossSh = 0.0f; }
    __syncthreads();
    unsigned wloc = 0;
    for (int j = tid; j < M; j += 256)
        wloc += (sgn == 0) ? (mSaSb[j] - commonW[j]) : commonW[j];
    if (wloc) atomicAdd(&wsumSh, wloc);
    __syncthreads();
    const unsigned wsum = wsumSh;
    if (wsum > 0) {
        const double inv = 1.0 / (double)wsum;
        float lloc = 0.0f;
        for (int j = tid; j < M; j += 256) {
            unsigned w = (sgn == 0) ? (mSaSb[j] - commonW[j]) : commonW[j];
            if (!w) continue;
            int e = mEd[j];
            int a, b; edge_ab(e, a, b);
            int nfg = (int)(!bgS[a]) + (int)(!bgS[b]);
            bool keep = (sgn == 0) ? (nfg == 0) : (nfg >= 1);
            if (!keep) continue;
            float wn = (float)((double)w * inv);
            float fa, fb;
            if (sgn == 0) { fa = pT[a] * pT[a];            fb = pT[b] * pT[b]; }
            else { float da = 20.0f - pT[a], db = 20.0f - pT[b]; fa = da * da; fb = db * db; }
            lloc += wn * (fa + fb);
        }
        if (lloc != 0.0f) atomicAdd(&lossSh, lloc);
        __syncthreads();
        if (tid == 0 && lossSh != 0.0f) atomicAdd(out, lossSh);
    }
}

extern "C" void kernel_launch(void* const* d_in, const int* in_sizes, int n_in,
                              void* d_out, int out_size, void* d_ws, size_t ws_size,
                              hipStream_t stream) {
    const float* y_true = (const float*)d_in[0];
    const float* y_pred = (const float*)d_in[1];
    float* out = (float*)d_out;
    const int B  = in_sizes[0] / (256 * 256);
    const int nW = B * 64 * 2;

    hipMemsetAsync(d_out, 0, (size_t)out_size * sizeof(float), stream);
    hipLaunchKernelGGL(malis_all, dim3(nW), dim3(256), 0, stream, y_true, y_pred, out);
}

// Round 14
// 269.919 us; speedup vs baseline: 1.0725x; 1.0725x over previous
//
#include <hip/hip_runtime.h>

#define NPIX   1024   // 32*32
#define NEH    992    // horizontal edges 32*31
#define NEDGE  1984   // + vertical 31*32
#define SORTN  2048
#define CHUNK  8      // labels per phase-2 pass
#define NMERGE 1023
#define NIL    0xFFFFu

__device__ __forceinline__ void edge_ab(int e, int& a, int& b) {
    if (e < NEH) { int y = e / 31; int x = e - y * 31; a = y * 32 + x; b = a + 1; }
    else         { int ev = e - NEH; a = ev; b = ev + 32; }
}

__device__ __forceinline__ uint4 add4(uint4 x, uint4 y) {
    return make_uint4(x.x + y.x, x.y + y.y, x.z + y.z, x.w + y.w);
}
__device__ __forceinline__ uint4 sub4(uint4 x, uint4 y) {
    return make_uint4(x.x - y.x, x.y - y.y, x.z - y.z, x.w - y.w);
}

// wave-uniform broadcast via v_readlane (VALU/SALU class; no LDS round-trip)
__device__ __forceinline__ unsigned rdl32(unsigned v, int lane) {
    return (unsigned)__builtin_amdgcn_readlane((int)v, lane);
}
__device__ __forceinline__ unsigned long long rdl64(unsigned long long v, int lane) {
    unsigned lo = (unsigned)__builtin_amdgcn_readlane((int)(unsigned)v, lane);
    unsigned hi = (unsigned)__builtin_amdgcn_readlane((int)(unsigned)(v >> 32), lane);
    return ((unsigned long long)hi << 32) | lo;
}

// ============================ fused K1/K2 bodies ============================
__device__ void ccl_body(char* smem, int* kprimeSh,
                         const float* __restrict__ t_glob,
                         unsigned short* __restrict__ pixLab_g,
                         int* __restrict__ Kg, int tileId) {
    const int tid = threadIdx.x;
    const int bat = tileId >> 6;
    const int tile = tileId & 63;
    const int tr = tile >> 3, tc = tile & 7;

    unsigned short* labS = (unsigned short*)smem;                 // [0,2048)
    unsigned int*   cntS = (unsigned int*)(smem + 2048);          // [2048,6144)
    unsigned char*  bgS  = (unsigned char*)(smem + 20480);        // [20480,21504)

    for (int i = tid; i < NPIX; i += 256) {
        int y = i >> 5, x = i & 31;
        int gidx = bat * 65536 + (tr * 32 + y) * 256 + (tc * 32 + x);
        bgS[i] = (t_glob[gidx] == 0.0f) ? 1 : 0;
    }
    __syncthreads();

    if (tid < 64) {
        const int lane = tid;
        if (lane < 32) {
            #pragma unroll
            for (int x = 0; x < 32; x++) {
                int i = lane * 32 + x;
                labS[i] = bgS[i] ? (unsigned short)i : (unsigned short)NIL;
            }
        }
        while (true) {
            bool changed = false;
            if (lane < 32) {
                const int base = lane * 32;
                unsigned short v[32];
                #pragma unroll
                for (int x = 0; x < 32; x++) v[x] = labS[base + x];
                unsigned run = NIL;
                #pragma unroll
                for (int x = 0; x < 32; x++) {
                    unsigned val = v[x];
                    if (val == NIL) { run = NIL; }
                    else { unsigned nv = min(run, val); changed |= (nv != val); v[x] = (unsigned short)nv; run = nv; }
                }
                run = NIL;
                #pragma unroll
                for (int x = 31; x >= 0; x--) {
                    unsigned val = v[x];
                    if (val == NIL) { run = NIL; }
                    else { unsigned nv = min(run, val); changed |= (nv != val); v[x] = (unsigned short)nv; run = nv; }
                }
                #pragma unroll
                for (int x = 0; x < 32; x++) labS[base + x] = v[x];
            }
            if (lane < 32) {
                unsigned short c[32];
                #pragma unroll
                for (int k = 0; k < 32; k++) c[k] = labS[k * 32 + lane];
                unsigned run = NIL;
                #pragma unroll
                for (int k = 0; k < 32; k++) {
                    unsigned val = c[k];
                    if (val == NIL) { run = NIL; }
                    else { unsigned nv = min(run, val); changed |= (nv != val); c[k] = (unsigned short)nv; run = nv; }
                }
                run = NIL;
                #pragma unroll
                for (int k = 31; k >= 0; k--) {
                    unsigned val = c[k];
                    if (val == NIL) { run = NIL; }
                    else { unsigned nv = min(run, val); changed |= (nv != val); c[k] = (unsigned short)nv; run = nv; }
                }
                #pragma unroll
                for (int k = 0; k < 32; k++) labS[k * 32 + lane] = c[k];
            }
            if (!__any(changed)) break;
        }
    }
    __syncthreads();

    for (int i = tid; i < NPIX; i += 256) cntS[i] = 0;
    if (tid == 0) *kprimeSh = 0;
    __syncthreads();
    for (int i = tid; i < NPIX; i += 256)
        if (bgS[i]) atomicAdd(&cntS[labS[i]], 1u);
    __syncthreads();
    for (int i = tid; i < NPIX; i += 256) {
        if (bgS[i] && (int)labS[i] == i) {
            unsigned id = (cntS[i] >= 2) ? (unsigned)atomicAdd(kprimeSh, 1) : NIL;
            cntS[i] = id;
        }
    }
    __syncthreads();
    for (int i = tid; i < NPIX; i += 256)
        pixLab_g[tileId * NPIX + i] = bgS[i] ? (unsigned short)cntS[labS[i]] : (unsigned short)NIL;
    if (tid == 0) Kg[tileId] = *kprimeSh;
}

__device__ void sort_body(char* smem,
                          const float* __restrict__ t_glob,
                          const float* __restrict__ p_glob,
                          unsigned short* __restrict__ ord_g, int wg) {
    const int tid = threadIdx.x;
    const int sgn = wg & 1;
    const int tileId = wg >> 1;
    const int bat = tileId >> 6;
    const int tile = tileId & 63;
    const int tr = tile >> 3, tc = tile & 7;

    float*              pT   = (float*)smem;                      // [0,4096)
    unsigned long long* keys = (unsigned long long*)(smem + 4096);// [4096,20480)
    unsigned char*      bgS  = (unsigned char*)(smem + 20480);    // [20480,21504)

    for (int i = tid; i < NPIX; i += 256) {
        int y = i >> 5, x = i & 31;
        int gidx = bat * 65536 + (tr * 32 + y) * 256 + (tc * 32 + x);
        pT[i] = p_glob[gidx];
        bgS[i] = (t_glob[gidx] == 0.0f) ? 1 : 0;
    }
    __syncthreads();

    for (int k = tid; k < SORTN; k += 256) {
        unsigned long long key = 0ULL;
        if (k < NEDGE) {
            int a, b; edge_ab(k, a, b);
            float cost = pT[a] + pT[b];
            int nfg = (int)(!bgS[a]) + (int)(!bgS[b]);
            if (sgn == 0) { if (nfg == 2) cost = 20.0f; }
            else          { if (nfg == 0) cost = 0.0f;  }
            key = ((unsigned long long)__float_as_uint(cost) << 16)
                | (unsigned long long)(0xFFFFu - (unsigned)k);
        }
        keys[k] = key;
    }
    __syncthreads();
    for (int kk = 2; kk <= SORTN; kk <<= 1) {
        for (int jj = kk >> 1; jj > 0; jj >>= 1) {
            for (int i = tid; i < SORTN; i += 256) {
                int ixj = i ^ jj;
                if (ixj > i) {
                    unsigned long long A = keys[i], Bv = keys[ixj];
                    bool descBlk = ((i & kk) == 0);
                    if ((A < Bv) == descBlk) { keys[i] = Bv; keys[ixj] = A; }
                }
            }
            __syncthreads();
        }
    }
    for (int k = tid; k < NEDGE; k += 256)
        ord_g[(size_t)wg * SORTN + k] = (unsigned short)(0xFFFFu - (unsigned)(keys[k] & 0xFFFFULL));
}

__global__ __launch_bounds__(256, 2)
void k12_ccl_sort(const float* __restrict__ t_glob,
                  const float* __restrict__ p_glob,
                  unsigned short* __restrict__ pixLab_g,
                  int* __restrict__ Kg,
                  unsigned short* __restrict__ ord_g,
                  int nT) {
    __shared__ __align__(16) char smem[21504];
    __shared__ int kprimeSh;
    if ((int)blockIdx.x < nT)
        ccl_body(smem, &kprimeSh, t_glob, pixLab_g, Kg, blockIdx.x);
    else
        sort_body(smem, t_glob, p_glob, ord_g, blockIdx.x - nT);
}

// ============================ K34: fused Kruskal + weights + loss ============================
// Wave 0: hybrid Kruskal. Bulk = gen-tagged priority-claim rounds (no clear phase).
// Tail = chain-scan when all pending candidates touch one common root R; else
// serial register-log fallback. Exact serial-Kruskal record equivalence.
__global__ __launch_bounds__(256, 2)
void k34_fused(const float* __restrict__ t_glob,
               const float* __restrict__ p_glob,
               const unsigned short* __restrict__ pixLab_g,
               const int* __restrict__ Kg,
               const unsigned short* __restrict__ ord_g,
               float* __restrict__ out) {
    const int tid = threadIdx.x;
    const int wg  = blockIdx.x;
    const int sgn = wg & 1;
    const int tileId = wg >> 1;
    const int bat = tileId >> 6;
    const int tile = tileId & 63;
    const int tr = tile >> 3, tc = tile & 7;

    __shared__ unsigned short parentS[NPIX];
    __shared__ unsigned long long nodeS[NPIX];
    __shared__ unsigned short nextS[NPIX];
    __shared__ unsigned int   mRecA[NMERGE];
    __shared__ unsigned int   mRecB[NMERGE];
    __shared__ unsigned int   mSaSb[NMERGE];
    __shared__ unsigned int   commonW[NMERGE];
    __shared__ unsigned short mEd[NMERGE];
    __shared__ float          pT[NPIX];
    __shared__ unsigned char  bgS[NPIX];
    __shared__ unsigned short pixLab[NPIX];
    __shared__ unsigned short posS[NPIX];
    __shared__ unsigned int   claimS[NPIX];                 // gen-tagged, never cleared
    __shared__ __align__(16) unsigned long long big[2564];
    __shared__ int   mCountSh;
    __shared__ unsigned wsumSh;
    __shared__ float lossSh;

    const unsigned short* ord = ord_g + (size_t)wg * SORTN;

    // ---- init (all 256 threads) ----
    for (int i = tid; i < NPIX; i += 256) {
        int y = i >> 5, x = i & 31;
        int gidx = bat * 65536 + (tr * 32 + y) * 256 + (tc * 32 + x);
        float tv = t_glob[gidx];
        unsigned bg = (tv == 0.0f) ? 1u : 0u;
        pT[i] = p_glob[gidx];
        bgS[i] = (unsigned char)bg;
        pixLab[i] = pixLab_g[tileId * NPIX + i];
        parentS[i] = (unsigned short)i;
        nodeS[i] = ((unsigned long long)i << 48) | ((unsigned long long)i << 32)
                 | (1ULL << 16) | (unsigned long long)bg;
        nextS[i] = (unsigned short)NIL;
        claimS[i] = 0xFFFFFFFFu;
    }
    __syncthreads();

    // ---- Kruskal on wave 0 ----
    if (tid < 64) {
        const int lane = tid;
        int m = 0;
        unsigned gen = 1u << 24;                         // strictly decreasing claim gen
        for (int kb = 0; kb < NEDGE; kb += 64) {         // 31 exact batches
            int e = ord[kb + lane];
            int a, b; edge_ab(e, a, b);
            unsigned ra = (unsigned)a, rb = (unsigned)b;
            while (true) {                               // concurrent path-halving find
                unsigned pa = parentS[ra];
                unsigned pb = parentS[rb];
                if (pa == ra && pb == rb) break;
                if (pa != ra) { unsigned ga = parentS[pa]; parentS[ra] = (unsigned short)ga; ra = ga; }
                if (pb != rb) { unsigned gb = parentS[pb]; parentS[rb] = (unsigned short)gb; rb = gb; }
            }
            bool pending = (ra != rb);
            bool committed = false;
            unsigned recA = 0, recB = 0, recSS = 0;

            // ---- bulk gen-tagged claim rounds ----
            int winners = 64;
            while (__any(pending) && winners >= 6) {
                gen--;
                unsigned myval = (gen << 6) | (unsigned)lane;
                if (pending) {
                    atomicMin(&claimS[ra], myval);
                    atomicMin(&claimS[rb], myval);
                }
                bool win = pending && (claimS[ra] == myval) && (claimS[rb] == myval);
                if (win) {
                    unsigned long long nA = nodeS[ra], nB = nodeS[rb];
                    unsigned cons = ra, surv = rb;
                    unsigned szAu = (unsigned)(nA >> 16) & 0xFFFFu;
                    unsigned szBu = (unsigned)(nB >> 16) & 0xFFFFu;
                    if (szAu > szBu) {
                        unsigned t = cons; cons = surv; surv = t;
                        unsigned long long tn = nA; nA = nB; nB = tn;
                    }
                    unsigned headA = (unsigned)(nA >> 48);
                    unsigned tailA = (unsigned)(nA >> 32) & 0xFFFFu;
                    unsigned szA   = (unsigned)(nA >> 16) & 0xFFFFu;
                    unsigned slA   = (unsigned)nA & 0xFFFFu;
                    unsigned headB = (unsigned)(nB >> 48);
                    unsigned tailB = (unsigned)(nB >> 32) & 0xFFFFu;
                    unsigned szB   = (unsigned)(nB >> 16) & 0xFFFFu;
                    unsigned slB   = (unsigned)nB & 0xFFFFu;
                    unsigned long long merged =
                          ((unsigned long long)headA << 48)
                        | ((unsigned long long)tailB << 32)
                        | ((unsigned long long)(szA + szB) << 16)
                        | (unsigned long long)(slA + slB);
                    parentS[cons] = (unsigned short)surv;
                    nodeS[surv]   = merged;
                    nextS[tailA]  = (unsigned short)headB;
                    recA = (headA << 16) | headB;
                    recB = (szA << 16) | szB;
                    recSS = slA * slB;
                    committed = true;
                    pending = false;
                }
                winners = (int)__popcll(__ballot(win));
                if (pending) {
                    while (true) {
                        unsigned pa = parentS[ra];
                        unsigned pb = parentS[rb];
                        if (pa == ra && pb == rb) break;
                        if (pa != ra) { unsigned ga = parentS[pa]; parentS[ra] = (unsigned short)ga; ra = ga; }
                        if (pb != rb) { unsigned gb = parentS[pb]; parentS[rb] = (unsigned short)gb; rb = gb; }
                    }
                    if (ra == rb) pending = false;
                }
            }

            unsigned long long cmB = __ballot(committed);
            if (committed) {
                int idx = m + (int)__popcll(cmB & ((1ULL << lane) - 1ULL));
                mRecA[idx] = recA;
                mRecB[idx] = recB;
                mSaSb[idx] = recSS;
                mEd[idx]   = (unsigned short)e;
            }
            m += (int)__popcll(cmB);

            // ---- tail ----
            int logCount = 0;
            unsigned long long candm0 = __ballot(pending);
            if (candm0 != 0ULL) {
                unsigned long long na = 0, nb = 0;
                if (pending) { na = nodeS[ra]; nb = nodeS[rb]; }   // fresh post-bulk
                int j0 = __ffsll((long long)candm0) - 1;
                unsigned Ra = rdl32(ra, j0), Rb = rdl32(rb, j0);
                unsigned long long mAc = __ballot(pending && (ra == Ra || rb == Ra));
                unsigned long long mBc = __ballot(pending && (ra == Rb || rb == Rb));
                unsigned R = (__popcll(mAc) >= __popcll(mBc)) ? Ra : Rb;
                bool onR  = pending && ((ra == R) != (rb == R));
                bool offR = pending && (ra != R) && (rb != R);

                if (!__any(offR)) {
                    // ======== chain-scan ========
                    unsigned cons = 0;
                    unsigned long long cnode = 0;
                    if (onR) { cons = (ra == R) ? rb : ra; cnode = (ra == R) ? nb : na; }
                    gen--;
                    unsigned myval = (gen << 6) | (unsigned)lane;
                    if (onR) atomicMin(&claimS[cons], myval);
                    bool valid = onR && (claimS[cons] == myval);   // dedup: losers are cycle-skips
                    unsigned long long vm = __ballot(valid);
                    if (vm != 0ULL) {
                        unsigned long long rnode = (R == Ra) ? rdl64(na, j0) : rdl64(nb, j0);
                        unsigned headR0 = (unsigned)(rnode >> 48);
                        unsigned tailR0 = (unsigned)(rnode >> 32) & 0xFFFFu;
                        unsigned szR0   = (unsigned)(rnode >> 16) & 0xFFFFu;
                        unsigned slR0   = (unsigned)rnode & 0xFFFFu;
                        unsigned headA = valid ? (unsigned)(cnode >> 48) : 0u;
                        unsigned tailA = valid ? (unsigned)(cnode >> 32) & 0xFFFFu : 0u;
                        unsigned szA   = valid ? (unsigned)(cnode >> 16) & 0xFFFFu : 0u;
                        unsigned slA   = valid ? (unsigned)cnode & 0xFFFFu : 0u;
                        unsigned s1 = szA, s2 = slA;           // inclusive scans
                        #pragma unroll
                        for (int d = 1; d < 64; d <<= 1) {
                            unsigned o1 = __shfl_up(s1, d, 64);
                            unsigned o2 = __shfl_up(s2, d, 64);
                            if (lane >= d) { s1 += o1; s2 += o2; }
                        }
                        unsigned szPre = s1 - szA, slPre = s2 - slA;    // exclusive
                        unsigned long long below = vm & ((1ULL << lane) - 1ULL);
                        int pv = 63 - (int)__clzll((long long)(below | 1ULL));
                        unsigned hprev = __shfl(headA, below ? pv : 0, 64);
                        unsigned headB = below ? hprev : headR0;
                        unsigned szB = szR0 + szPre;
                        unsigned slB = slR0 + slPre;
                        if (valid) {
                            parentS[cons] = (unsigned short)R;
                            nextS[tailA]  = (unsigned short)headB;
                            int idx = m + (int)__popcll(below);
                            mRecA[idx] = (headA << 16) | headB;
                            mRecB[idx] = (szA << 16) | szB;
                            mSaSb[idx] = slA * slB;
                            mEd[idx]   = (unsigned short)e;
                        }
                        int last = 63 - (int)__clzll((long long)vm);
                        if (valid && lane == last) {
                            nodeS[R] = ((unsigned long long)headA << 48)
                                     | ((unsigned long long)tailR0 << 32)
                                     | ((unsigned long long)(szR0 + s1) << 16)
                                     | (unsigned long long)(slR0 + s2);
                        }
                        logCount = (int)__popcll(vm);
                    }
                } else {
                    // ======== serial register-log fallback ========
                    unsigned specAB = (ra << 16) | rb;
                    unsigned long long candm = candm0;
                    unsigned logRa  = 0xFFFFFFFFu;
                    unsigned logRbO = 0xFFFFFFFFu;
                    unsigned curRoot = 0xFFFFFFFFu;
                    unsigned long long logNode = 0;
                    while (candm != 0ULL) {
                        int j = __ffsll((long long)candm) - 1;
                        candm &= candm - 1ULL;
                        unsigned sAB = rdl32(specAB, j);
                        unsigned cra = sAB >> 16;
                        unsigned crb = sAB & 0xFFFFu;
                        unsigned long long hitA = __ballot(logRa == cra);
                        unsigned long long hitB = __ballot(logRa == crb);
                        if (hitA) cra = rdl32(curRoot, __ffsll((long long)hitA) - 1);
                        if (hitB) crb = rdl32(curRoot, __ffsll((long long)hitB) - 1);
                        if (cra == crb) continue;
                        unsigned ce = rdl32((unsigned)e, j);
                        unsigned long long hbA = __ballot(logRbO == cra);
                        unsigned long long hbB = __ballot(logRbO == crb);
                        unsigned long long cna = hbA ? rdl64(logNode, 63 - __clzll((long long)hbA)) : rdl64(na, j);
                        unsigned long long cnb = hbB ? rdl64(logNode, 63 - __clzll((long long)hbB)) : rdl64(nb, j);
                        unsigned cons = cra, surv = crb;
                        unsigned szAq = (unsigned)(cna >> 16) & 0xFFFFu;
                        unsigned szBq = (unsigned)(cnb >> 16) & 0xFFFFu;
                        if (szAq > szBq) {
                            unsigned t = cons; cons = surv; surv = t;
                            unsigned long long tn = cna; cna = cnb; cnb = tn;
                        }
                        unsigned headA = (unsigned)(cna >> 48);
                        unsigned tailA = (unsigned)(cna >> 32) & 0xFFFFu;
                        unsigned szA   = (unsigned)(cna >> 16) & 0xFFFFu;
                        unsigned slA   = (unsigned)cna & 0xFFFFu;
                        unsigned headB = (unsigned)(cnb >> 48);
                        unsigned tailB = (unsigned)(cnb >> 32) & 0xFFFFu;
                        unsigned szB   = (unsigned)(cnb >> 16) & 0xFFFFu;
                        unsigned slB   = (unsigned)cnb & 0xFFFFu;
                        unsigned long long merged =
                              ((unsigned long long)headA << 48)
                            | ((unsigned long long)tailB << 32)
                            | ((unsigned long long)(szA + szB) << 16)
                            | (unsigned long long)(slA + slB);
                        if (curRoot == cons) curRoot = surv;
                        if (lane == logCount) {
                            logRa = cons; logRbO = surv; curRoot = surv; logNode = merged;
                            parentS[cons] = (unsigned short)surv;
                            nodeS[surv]   = merged;
                            nextS[tailA]  = (unsigned short)headB;
                            int idx = m + logCount;
                            mRecA[idx] = (headA << 16) | headB;
                            mRecB[idx] = (szA << 16) | szB;
                            mSaSb[idx] = slA * slB;
                            mEd[idx]   = (unsigned short)ce;
                        }
                        logCount++;
                    }
                }
            }
            m += logCount;
        }
        if (lane == 0) mCountSh = m;
    }
    __syncthreads();
    const int M = mCountSh;
    const int K = Kg[tileId];
    for (int j = tid; j < M; j += 256) commonW[j] = 0;

    // ---- Wyllie list ranking -> posS ----
    unsigned short* n0 = (unsigned short*)big;
    unsigned short* n1 = n0 + 1024;
    unsigned short* d0 = n0 + 2048;
    unsigned short* d1 = n0 + 3072;
    for (int i = tid; i < NPIX; i += 256) { n0[i] = nextS[i]; d0[i] = 1; }
    __syncthreads();
    for (int s = 0; s < 10; s++) {
        unsigned short* sn = (s & 1) ? n1 : n0;
        unsigned short* sd = (s & 1) ? d1 : d0;
        unsigned short* dn = (s & 1) ? n0 : n1;
        unsigned short* dd = (s & 1) ? d0 : d1;
        for (int i = tid; i < NPIX; i += 256) {
            unsigned nx = sn[i];
            unsigned dv = sd[i];
            if (nx != NIL) { dv += sd[nx]; nx = sn[nx]; }
            dn[i] = (unsigned short)nx;
            dd[i] = (unsigned short)dv;
        }
        __syncthreads();
    }
    for (int i = tid; i < NPIX; i += 256)
        posS[i] = (unsigned short)(NPIX - (int)d0[i]);
    __syncthreads();

    // ---- chunked label prefix sums + per-merge dots ----
    unsigned*       P32 = (unsigned*)big;
    uint4*          P4  = (uint4*)big;
    unsigned*       scr = P32 + 4100;
    uint4*          S4  = (uint4*)scr;
    unsigned short* P16 = (unsigned short*)big;
    for (int base = 0; base < K; base += CHUNK) {
        for (int idx = tid; idx < 4100; idx += 256) P32[idx] = 0;
        __syncthreads();
        for (int i = tid; i < NPIX; i += 256) {
            unsigned l = pixLab[i];
            if (l != NIL && l >= (unsigned)base && l < (unsigned)(base + CHUNK))
                P16[(posS[i] + 1) * 8 + (l - base)] = 1;
        }
        __syncthreads();
        {
            int r0 = tid * 4 + 1;
            uint4 acc = P4[r0];
            for (int rr = r0 + 1; rr <= r0 + 3; rr++) { acc = add4(acc, P4[rr]); P4[rr] = acc; }
            S4[tid] = acc;
            __syncthreads();
            if (tid < 64) {
                uint4 s0 = S4[tid * 4], s1 = S4[tid * 4 + 1], s2 = S4[tid * 4 + 2], s3 = S4[tid * 4 + 3];
                uint4 t1 = add4(s0, s1), t2 = add4(t1, s2), t3 = add4(t2, s3);
                uint4 run = t3;
                #pragma unroll
                for (int d = 1; d < 64; d <<= 1) {
                    uint4 o;
                    o.x = __shfl_up(run.x, d, 64);
                    o.y = __shfl_up(run.y, d, 64);
                    o.z = __shfl_up(run.z, d, 64);
                    o.w = __shfl_up(run.w, d, 64);
                    if (tid >= d) run = add4(run, o);
                }
                uint4 off = sub4(run, t3);
                S4[tid * 4]     = add4(s0, off);
                S4[tid * 4 + 1] = add4(t1, off);
                S4[tid * 4 + 2] = add4(t2, off);
                S4[tid * 4 + 3] = add4(t3, off);
            }
            __syncthreads();
            if (tid > 0) {
                uint4 off = S4[tid - 1];
                for (int rr = r0; rr <= r0 + 3; rr++) P4[rr] = add4(P4[rr], off);
            }
        }
        __syncthreads();
        for (int j = tid; j < M; j += 256) {
            unsigned recA = mRecA[j], recB = mRecB[j];
            unsigned aS = posS[recA >> 16];
            unsigned bS = posS[recA & 0xFFFFu];
            uint4 da = sub4(P4[aS + (recB >> 16)], P4[aS]);
            uint4 db = sub4(P4[bS + (recB & 0xFFFFu)], P4[bS]);
            unsigned acc;
            acc  = (da.x & 0xFFFFu) * (db.x & 0xFFFFu) + (da.x >> 16) * (db.x >> 16);
            acc += (da.y & 0xFFFFu) * (db.y & 0xFFFFu) + (da.y >> 16) * (db.y >> 16);
            acc += (da.z & 0xFFFFu) * (db.z & 0xFFFFu) + (da.z >> 16) * (db.z >> 16);
            acc += (da.w & 0xFFFFu) * (db.w & 0xFFFFu) + (da.w >> 16) * (db.w >> 16);
            commonW[j] += acc;
        }
        __syncthreads();
    }

    // ---- normalize + mask + loss ----
    if (tid == 0) { wsumSh = 0; lossSh = 0.0f; }
    __syncthreads();
    unsigned wloc = 0;
    for (int j = tid; j < M; j += 256)
        wloc += (sgn == 0) ? (mSaSb[j] - commonW[j]) : commonW[j];
    if (wloc) atomicAdd(&wsumSh, wloc);
    __syncthreads();
    const unsigned wsum = wsumSh;
    if (wsum > 0) {
        const double inv = 1.0 / (double)wsum;
        float lloc = 0.0f;
        for (int j = tid; j < M; j += 256) {
            unsigned w = (sgn == 0) ? (mSaSb[j] - commonW[j]) : commonW[j];
            if (!w) continue;
            int e = mEd[j];
            int a, b; edge_ab(e, a, b);
            int nfg = (int)(!bgS[a]) + (int)(!bgS[b]);
            bool keep = (sgn == 0) ? (nfg == 0) : (nfg >= 1);
            if (!keep) continue;
            float wn = (float)((double)w * inv);
            float fa, fb;
            if (sgn == 0) { fa = pT[a] * pT[a];            fb = pT[b] * pT[b]; }
            else { float da = 20.0f - pT[a], db = 20.0f - pT[b]; fa = da * da; fb = db * db; }
            lloc += wn * (fa + fb);
        }
        if (lloc != 0.0f) atomicAdd(&lossSh, lloc);
        __syncthreads();
        if (tid == 0 && lossSh != 0.0f) atomicAdd(out, lossSh);
    }
}

// ============================ fallback: monolith (used if ws too small) ============================
__global__ __launch_bounds__(256, 2)
void malis_mono(const float* __restrict__ t_glob,
                const float* __restrict__ p_glob,
                float* __restrict__ out) {
    const int tid  = threadIdx.x;
    const int wg   = blockIdx.x;
    const int sgn  = wg & 1;
    const int tileId = wg >> 1;
    const int bat  = tileId >> 6;
    const int tile = tileId & 63;
    const int tr = tile >> 3, tc = tile & 7;

    __shared__ float          pT[NPIX];
    __shared__ unsigned char  bgS[NPIX];
    __shared__ unsigned short pixLab[NPIX];
    __shared__ unsigned short parentS[NPIX];
    __shared__ unsigned short nextS[NPIX];
    __shared__ unsigned long long nodeS[NPIX];
    __shared__ unsigned int   claimS[NPIX];
    __shared__ unsigned short posS[NPIX];
    __shared__ unsigned short orderS[NEDGE];
    __shared__ unsigned int   mRecA[NMERGE];
    __shared__ unsigned int   mRecB[NMERGE];
    __shared__ unsigned short mEd[NMERGE];
    __shared__ unsigned int   mSaSb[NMERGE];
    __shared__ unsigned int   commonW[NMERGE];
    __shared__ __align__(16) unsigned long long big[2564];
    __shared__ int   kprimeSh, mCountSh;
    __shared__ unsigned wsumSh;
    __shared__ float lossSh;

    for (int i = tid; i < NPIX; i += 256) {
        int y = i >> 5, x = i & 31;
        int gidx = bat * 65536 + (tr * 32 + y) * 256 + (tc * 32 + x);
        pT[i] = p_glob[gidx];
        bgS[i] = (t_glob[gidx] == 0.0f) ? 1 : 0;
    }
    __syncthreads();

    unsigned short* labS = (unsigned short*)big;
    unsigned int*   cntS = (unsigned int*)(((char*)big) + 2048);
    if (tid < 64) {
        const int lane = tid;
        if (lane < 32) {
            #pragma unroll
            for (int x = 0; x < 32; x++) {
                int i = lane * 32 + x;
                labS[i] = bgS[i] ? (unsigned short)i : (unsigned short)NIL;
            }
        }
        while (true) {
            bool changed = false;
            if (lane < 32) {
                const int base = lane * 32;
                unsigned short v[32];
                #pragma unroll
                for (int x = 0; x < 32; x++) v[x] = labS[base + x];
                unsigned run = NIL;
                #pragma unroll
                for (int x = 0; x < 32; x++) {
                    unsigned val = v[x];
                    if (val == NIL) { run = NIL; }
                    else { unsigned nv = min(run, val); changed |= (nv != val); v[x] = (unsigned short)nv; run = nv; }
                }
                run = NIL;
                #pragma unroll
                for (int x = 31; x >= 0; x--) {
                    unsigned val = v[x];
                    if (val == NIL) { run = NIL; }
                    else { unsigned nv = min(run, val); changed |= (nv != val); v[x] = (unsigned short)nv; run = nv; }
                }
                #pragma unroll
                for (int x = 0; x < 32; x++) labS[base + x] = v[x];
            }
            if (lane < 32) {
                unsigned short c[32];
                #pragma unroll
                for (int k = 0; k < 32; k++) c[k] = labS[k * 32 + lane];
                unsigned run = NIL;
                #pragma unroll
                for (int k = 0; k < 32; k++) {
                    unsigned val = c[k];
                    if (val == NIL) { run = NIL; }
                    else { unsigned nv = min(run, val); changed |= (nv != val); c[k] = (unsigned short)nv; run = nv; }
                }
                run = NIL;
                #pragma unroll
                for (int k = 31; k >= 0; k--) {
                    unsigned val = c[k];
                    if (val == NIL) { run = NIL; }
                    else { unsigned nv = min(run, val); changed |= (nv != val); c[k] = (unsigned short)nv; run = nv; }
                }
                #pragma unroll
                for (int k = 0; k < 32; k++) labS[k * 32 + lane] = c[k];
            }
            if (!__any(changed)) break;
        }
    }
    __syncthreads();

    for (int i = tid; i < NPIX; i += 256) cntS[i] = 0;
    if (tid == 0) kprimeSh = 0;
    __syncthreads();
    for (int i = tid; i < NPIX; i += 256)
        if (bgS[i]) atomicAdd(&cntS[labS[i]], 1u);
    __syncthreads();
    for (int i = tid; i < NPIX; i += 256) {
        if (bgS[i] && (int)labS[i] == i) {
            unsigned id = (cntS[i] >= 2) ? (unsigned)atomicAdd(&kprimeSh, 1) : NIL;
            cntS[i] = id;
        }
    }
    __syncthreads();
    for (int i = tid; i < NPIX; i += 256)
        pixLab[i] = bgS[i] ? (unsigned short)cntS[labS[i]] : (unsigned short)NIL;
    __syncthreads();
    const int K = kprimeSh;

    unsigned long long* keys = big;
    for (int k = tid; k < SORTN; k += 256) {
        unsigned long long key = 0ULL;
        if (k < NEDGE) {
            int a, b; edge_ab(k, a, b);
            float cost = pT[a] + pT[b];
            int nfg = (int)(!bgS[a]) + (int)(!bgS[b]);
            if (sgn == 0) { if (nfg == 2) cost = 20.0f; }
            else          { if (nfg == 0) cost = 0.0f;  }
            key = ((unsigned long long)__float_as_uint(cost) << 16)
                | (unsigned long long)(0xFFFFu - (unsigned)k);
        }
        keys[k] = key;
    }
    __syncthreads();
    for (int kk = 2; kk <= SORTN; kk <<= 1) {
        for (int jj = kk >> 1; jj > 0; jj >>= 1) {
            for (int i = tid; i < SORTN; i += 256) {
                int ixj = i ^ jj;
                if (ixj > i) {
                    unsigned long long A = keys[i], Bv = keys[ixj];
                    bool descBlk = ((i & kk) == 0);
                    if ((A < Bv) == descBlk) { keys[i] = Bv; keys[ixj] = A; }
                }
            }
            __syncthreads();
        }
    }
    for (int k = tid; k < NEDGE; k += 256)
        orderS[k] = (unsigned short)(0xFFFFu - (unsigned)(keys[k] & 0xFFFFULL));
    for (int i = tid; i < NPIX; i += 256) {
        parentS[i] = (unsigned short)i;
        nodeS[i] = ((unsigned long long)i << 48) | ((unsigned long long)i << 32)
                 | (1ULL << 16) | (unsigned long long)bgS[i];
        nextS[i] = (unsigned short)NIL;
        claimS[i] = 0xFFFFFFFFu;
    }
    __syncthreads();

    if (tid < 64) {
        const int lane = tid;
        int m = 0;
        unsigned gen = 1u << 24;
        for (int kb = 0; kb < NEDGE; kb += 64) {
            int e = orderS[kb + lane];
            int a, b; edge_ab(e, a, b);
            unsigned ra = (unsigned)a, rb = (unsigned)b;
            while (true) {
                unsigned pa = parentS[ra];
                unsigned pb = parentS[rb];
                if (pa == ra && pb == rb) break;
                if (pa != ra) { unsigned ga = parentS[pa]; parentS[ra] = (unsigned short)ga; ra = ga; }
                if (pb != rb) { unsigned gb = parentS[pb]; parentS[rb] = (unsigned short)gb; rb = gb; }
            }
            bool pending = (ra != rb);
            bool committed = false;
            unsigned recA = 0, recB = 0, recSS = 0;
            int winners = 64;
            while (__any(pending) && winners >= 6) {
                gen--;
                unsigned myval = (gen << 6) | (unsigned)lane;
                if (pending) {
                    atomicMin(&claimS[ra], myval);
                    atomicMin(&claimS[rb], myval);
                }
                bool win = pending && (claimS[ra] == myval) && (claimS[rb] == myval);
                if (win) {
                    unsigned long long nA = nodeS[ra], nB = nodeS[rb];
                    unsigned cons = ra, surv = rb;
                    unsigned szAu = (unsigned)(nA >> 16) & 0xFFFFu;
                    unsigned szBu = (unsigned)(nB >> 16) & 0xFFFFu;
                    if (szAu > szBu) {
                        unsigned t = cons; cons = surv; surv = t;
                        unsigned long long tn = nA; nA = nB; nB = tn;
                    }
                    unsigned headA = (unsigned)(nA >> 48);
                    unsigned tailA = (unsigned)(nA >> 32) & 0xFFFFu;
                    unsigned szA   = (unsigned)(nA >> 16) & 0xFFFFu;
                    unsigned slA   = (unsigned)nA & 0xFFFFu;
                    unsigned headB = (unsigned)(nB >> 48);
                    unsigned tailB = (unsigned)(nB >> 32) & 0xFFFFu;
                    unsigned szB   = (unsigned)(nB >> 16) & 0xFFFFu;
                    unsigned slB   = (unsigned)nB & 0xFFFFu;
                    unsigned long long merged =
                          ((unsigned long long)headA << 48)
                        | ((unsigned long long)tailB << 32)
                        | ((unsigned long long)(szA + szB) << 16)
                        | (unsigned long long)(slA + slB);
                    parentS[cons] = (unsigned short)surv;
                    nodeS[surv]   = merged;
                    nextS[tailA]  = (unsigned short)headB;
                    recA = (headA << 16) | headB;
                    recB = (szA << 16) | szB;
                    recSS = slA * slB;
                    committed = true;
                    pending = false;
                }
                winners = (int)__popcll(__ballot(win));
                if (pending) {
                    while (true) {
                        unsigned pa = parentS[ra];
                        unsigned pb = parentS[rb];
                        if (pa == ra && pb == rb) break;
                        if (pa != ra) { unsigned ga = parentS[pa]; parentS[ra] = (unsigned short)ga; ra = ga; }
                        if (pb != rb) { unsigned gb = parentS[pb]; parentS[rb] = (unsigned short)gb; rb = gb; }
                    }
                    if (ra == rb) pending = false;
                }
            }
            unsigned long long cmB = __ballot(committed);
            if (committed) {
                int idx = m + (int)__popcll(cmB & ((1ULL << lane) - 1ULL));
                mRecA[idx] = recA;
                mRecB[idx] = recB;
                mSaSb[idx] = recSS;
                mEd[idx]   = (unsigned short)e;
            }
            m += (int)__popcll(cmB);

            int logCount = 0;
            unsigned long long candm0 = __ballot(pending);
            if (candm0 != 0ULL) {
                unsigned long long na = 0, nb = 0;
                if (pending) { na = nodeS[ra]; nb = nodeS[rb]; }
                unsigned specAB = (ra << 16) | rb;
                unsigned long long candm = candm0;
                unsigned logRa  = 0xFFFFFFFFu;
                unsigned logRbO = 0xFFFFFFFFu;
                unsigned curRoot = 0xFFFFFFFFu;
                unsigned long long logNode = 0;
                while (candm != 0ULL) {
                    int j = __ffsll((long long)candm) - 1;
                    candm &= candm - 1ULL;
                    unsigned sAB = rdl32(specAB, j);
                    unsigned cra = sAB >> 16;
                    unsigned crb = sAB & 0xFFFFu;
                    unsigned long long hitA = __ballot(logRa == cra);
                    unsigned long long hitB = __ballot(logRa == crb);
                    if (hitA) cra = rdl32(curRoot, __ffsll((long long)hitA) - 1);
                    if (hitB) crb = rdl32(curRoot, __ffsll((long long)hitB) - 1);
                    if (cra == crb) continue;
                    unsigned ce = rdl32((unsigned)e, j);
                    unsigned long long hbA = __ballot(logRbO == cra);
                    unsigned long long hbB = __ballot(logRbO == crb);
                    unsigned long long cna = hbA ? rdl64(logNode, 63 - __clzll((long long)hbA)) : rdl64(na, j);
                    unsigned long long cnb = hbB ? rdl64(logNode, 63 - __clzll((long long)hbB)) : rdl64(nb, j);
                    unsigned cons = cra, surv = crb;
                    unsigned szAq = (unsigned)(cna >> 16) & 0xFFFFu;
                    unsigned szBq = (unsigned)(cnb >> 16) & 0xFFFFu;
                    if (szAq > szBq) {
                        unsigned t = cons; cons = surv; surv = t;
                        unsigned long long tn = cna; cna = cnb; cnb = tn;
                    }
                    unsigned headA = (unsigned)(cna >> 48);
                    unsigned tailA = (unsigned)(cna >> 32) & 0xFFFFu;
                    unsigned szA   = (unsigned)(cna >> 16) & 0xFFFFu;
                    unsigned slA   = (unsigned)cna & 0xFFFFu;
                    unsigned headB = (unsigned)(cnb >> 48);
                    unsigned tailB = (unsigned)(cnb >> 32) & 0xFFFFu;
                    unsigned szB   = (unsigned)(cnb >> 16) & 0xFFFFu;
                    unsigned slB   = (unsigned)cnb & 0xFFFFu;
                    unsigned long long merged =
                          ((unsigned long long)headA << 48)
                        | ((unsigned long long)tailB << 32)
                        | ((unsigned long long)(szA + szB) << 16)
                        | (unsigned long long)(slA + slB);
                    if (curRoot == cons) curRoot = surv;
                    if (lane == logCount) {
                        logRa = cons; logRbO = surv; curRoot = surv; logNode = merged;
                        parentS[cons] = (unsigned short)surv;
                        nodeS[surv]   = merged;
                        nextS[tailA]  = (unsigned short)headB;
                        int idx = m + logCount;
                        mRecA[idx] = (headA << 16) | headB;
                        mRecB[idx] = (szA << 16) | szB;
                        mSaSb[idx] = slA * slB;
                        mEd[idx]   = (unsigned short)ce;
                    }
                    logCount++;
                }
            }
            m += logCount;
        }
        if (lane == 0) mCountSh = m;
    }
    __syncthreads();
    const int M = mCountSh;
    for (int j = tid; j < M; j += 256) commonW[j] = 0;

    unsigned short* n0 = (unsigned short*)big;
    unsigned short* n1 = n0 + 1024;
    unsigned short* d0 = n0 + 2048;
    unsigned short* d1 = n0 + 3072;
    for (int i = tid; i < NPIX; i += 256) { n0[i] = nextS[i]; d0[i] = 1; }
    __syncthreads();
    for (int s = 0; s < 10; s++) {
        unsigned short* sn = (s & 1) ? n1 : n0;
        unsigned short* sd = (s & 1) ? d1 : d0;
        unsigned short* dn = (s & 1) ? n0 : n1;
        unsigned short* dd = (s & 1) ? d0 : d1;
        for (int i = tid; i < NPIX; i += 256) {
            unsigned nx = sn[i];
            unsigned dv = sd[i];
            if (nx != NIL) { dv += sd[nx]; nx = sn[nx]; }
            dn[i] = (unsigned short)nx;
            dd[i] = (unsigned short)dv;
        }
        __syncthreads();
    }
    for (int i = tid; i < NPIX; i += 256)
        posS[i] = (unsigned short)(NPIX - (int)d0[i]);
    __syncthreads();

    unsigned*       P32 = (unsigned*)big;
    uint4*          P4  = (uint4*)big;
    unsigned*       scr = P32 + 4100;
    uint4*          S4  = (uint4*)scr;
    unsigned short* P16 = (unsigned short*)big;
    for (int base = 0; base < K; base += CHUNK) {
        for (int idx = tid; idx < 4100; idx += 256) P32[idx] = 0;
        __syncthreads();
        for (int i = tid; i < NPIX; i += 256) {
            unsigned l = pixLab[i];
            if (l != NIL && l >= (unsigned)base && l < (unsigned)(base + CHUNK))
                P16[(posS[i] + 1) * 8 + (l - base)] = 1;
        }
        __syncthreads();
        {
            int r0 = tid * 4 + 1;
            uint4 acc = P4[r0];
            for (int rr = r0 + 1; rr <= r0 + 3; rr++) { acc = add4(acc, P4[rr]); P4[rr] = acc; }
            S4[tid] = acc;
            __syncthreads();
            if (tid < 64) {
                uint4 s0 = S4[tid * 4], s1 = S4[tid * 4 + 1], s2 = S4[tid * 4 + 2], s3 = S4[tid * 4 + 3];
                uint4 t1 = add4(s0, s1), t2 = add4(t1, s2), t3 = add4(t2, s3);
                uint4 run = t3;
                #pragma unroll
                for (int d = 1; d < 64; d <<= 1) {
                    uint4 o;
                    o.x = __shfl_up(run.x, d, 64);
                    o.y = __shfl_up(run.y, d, 64);
                    o.z = __shfl_up(run.z, d, 64);
                    o.w = __shfl_up(run.w, d, 64);
                    if (tid >= d) run = add4(run, o);
                }
                uint4 off = sub4(run, t3);
                S4[tid * 4]     = add4(s0, off);
                S4[tid * 4 + 1] = add4(t1, off);
                S4[tid * 4 + 2] = add4(t2, off);
                S4[tid * 4 + 3] = add4(t3, off);
            }
            __syncthreads();
            if (tid > 0) {
                uint4 off = S4[tid - 1];
                for (int rr = r0; rr <= r0 + 3; rr++) P4[rr] = add4(P4[rr], off);
            }
        }
        __syncthreads();
        for (int j = tid; j < M; j += 256) {
            unsigned recA = mRecA[j], recB = mRecB[j];
            unsigned aS = posS[recA >> 16];
            unsigned bS = posS[recA & 0xFFFFu];
            uint4 da = sub4(P4[aS + (recB >> 16)], P4[aS]);
            uint4 db = sub4(P4[bS + (recB & 0xFFFFu)], P4[bS]);
            unsigned acc;
            acc  = (da.x & 0xFFFFu) * (db.x & 0xFFFFu) + (da.x >> 16) * (db.x >> 16);
            acc += (da.y & 0xFFFFu) * (db.y & 0xFFFFu) + (da.y >> 16) * (db.y >> 16);
            acc += (da.z & 0xFFFFu) * (db.z & 0xFFFFu) + (da.z >> 16) * (db.z >> 16);
            acc += (da.w & 0xFFFFu) * (db.w & 0xFFFFu) + (da.w >> 16) * (db.w >> 16);
            commonW[j] += acc;
        }
        __syncthreads();
    }

    if (tid == 0) { wsumSh = 0; lossSh = 0.0f; }
    __syncthreads();
    unsigned wloc = 0;
    for (int j = tid; j < M; j += 256)
        wloc += (sgn == 0) ? (mSaSb[j] - commonW[j]) : commonW[j];
    if (wloc) atomicAdd(&wsumSh, wloc);
    __syncthreads();
    const unsigned wsum = wsumSh;
    if (wsum > 0) {
        const double inv = 1.0 / (double)wsum;
        float lloc = 0.0f;
        for (int j = tid; j < M; j += 256) {
            unsigned w = (sgn == 0) ? (mSaSb[j] - commonW[j]) : commonW[j];
            if (!w) continue;
            int e = mEd[j];
            int a, b; edge_ab(e, a, b);
            int nfg = (int)(!bgS[a]) + (int)(!bgS[b]);
            bool keep = (sgn == 0) ? (nfg == 0) : (nfg >= 1);
            if (!keep) continue;
            float wn = (float)((double)w * inv);
            float fa, fb;
            if (sgn == 0) { fa = pT[a] * pT[a];            fb = pT[b] * pT[b]; }
            else { float da = 20.0f - pT[a], db = 20.0f - pT[b]; fa = da * da; fb = db * db; }
            lloc += wn * (fa + fb);
        }
        if (lloc != 0.0f) atomicAdd(&lossSh, lloc);
        __syncthreads();
        if (tid == 0 && lossSh != 0.0f) atomicAdd(out, lossSh);
    }
}

extern "C" void kernel_launch(void* const* d_in, const int* in_sizes, int n_in,
                              void* d_out, int out_size, void* d_ws, size_t ws_size,
                              hipStream_t stream) {
    const float* y_true = (const float*)d_in[0];
    const float* y_pred = (const float*)d_in[1];
    float* out = (float*)d_out;
    const int B  = in_sizes[0] / (256 * 256);
    const int nT = B * 64;
    const int nW = nT * 2;

    const size_t offK   = (size_t)nT * 2048;
    const size_t offOrd = offK + (((size_t)nT * 4 + 255) & ~(size_t)255);
    const size_t need   = offOrd + (size_t)nW * 4096;

    hipMemsetAsync(d_out, 0, (size_t)out_size * sizeof(float), stream);

    if (ws_size >= need) {
        char* ws = (char*)d_ws;
        unsigned short* pixLab_g = (unsigned short*)ws;
        int*            Kg       = (int*)(ws + offK);
        unsigned short* ord_g    = (unsigned short*)(ws + offOrd);
        hipLaunchKernelGGL(k12_ccl_sort, dim3(nT + nW), dim3(256), 0, stream,
                           y_true, y_pred, pixLab_g, Kg, ord_g, nT);
        hipLaunchKernelGGL(k34_fused,    dim3(nW), dim3(256), 0, stream,
                           y_true, y_pred, pixLab_g, Kg, ord_g, out);
    } else {
        hipLaunchKernelGGL(malis_mono, dim3(nW), dim3(256), 0, stream, y_true, y_pred, out);
    }
}